// Round 8
// baseline (1100.187 us; speedup 1.0000x reference)
//
#include <hip/hip_runtime.h>
#include <hip/hip_fp16.h>
#include <math.h>

#ifndef M_PI
#define M_PI 3.14159265358979323846
#endif

// Problem constants
#define BB 2
#define VV 180
#define RR 32
#define CC 512
#define NPIX 512

#define PADL 106     // left padding of t-range
#define PW 724       // padded width: t_real in [-106, 617]
#define TCEN 362     // recentering offset for table indexing

// pair-orbit backprojection tiling
#define SH3 8        // rep-rows per block
#define CHP 2        // angle-PAIRS per LDS chunk
#define NCHP 45      // 45 * 2 = 90 pairs = 180 angles

// fallback tiling (round-3 kernels)
#define SH 16
#define CH2 6
#define NCHUNK2 30

// ws layout (floats):
//   [0,1024)      h_ext (impulse response, duplicated, scaled by pi/V)
//   [1024,1384)   legacy trig: cos[180] | sin[180]          (fallback path)
//   [1408,1768)   trig2: interleaved (cos,sin) float2[180]  (pair path uses first 90)
//   [2048,6144)   h4 quad table: float4 h4[x] = (h[x],h[x-1],h[x-2],h[x-3])
//   [6144,...)    pair path: fp16 table [64 slices][90 pairs][724] uint2 = 33.4 MB
//                   entry.x = half2(f0_v, f0_w), entry.y = half2(d_v, d_w)
//                   (pk-SPLIT layout: values word + slopes word)
//   fallback:     filt at [2048,...) (h4 NOT written in fallback mode)
#define H4_OFF 2048
#define TAB_OFF 6144
#define FILT_OFF 2048

typedef float f32x2 __attribute__((ext_vector_type(2)));

static __device__ __forceinline__ f32x2 mk2(float a, float b) {
    f32x2 r; r.x = a; r.y = b; return r;
}

// R2-verbatim fp16 unpack (proven clean codegen: 135 MB hbm, no spill).
// NO f16x2 ext_vector components, NO fpext-into-fma pattern, NO inline asm
// (every one of those scratch-spilled the accumulators in R3/R5/R6).
static __device__ __forceinline__ float2 unpack_h2(unsigned int u) {
    __half2 h = *reinterpret_cast<__half2*>(&u);
    return __half22float2(h);
}

// sample pair (v, v+90) = (f0_v,f0_w) + r*(d_v,d_w): ONE v_pk_fma_f32 on
// f32 values produced by the clean unpack. R4-proven elementwise-fma form.
static __device__ __forceinline__ f32x2 sample2(float r, uint2 q) {
    float2 f0 = unpack_h2(q.x);   // (f0_v, f0_w)
    float2 d  = unpack_h2(q.y);   // (d_v,  d_w)
    return __builtin_elementwise_fma(mk2(r, r), mk2(d.x, d.y), mk2(f0.x, f0.y));
}

// ---------------------------------------------------------------------------
// Kernel A: ramp-filter impulse response h[k] (scaled by pi/V) + angle tables.
// ---------------------------------------------------------------------------
__global__ void precompute_kernel(float* __restrict__ ws) {
    int j = blockIdx.x * blockDim.x + threadIdx.x;  // 0..511
    if (j < 512) {
        float s = 0.f;
        for (int m = 1; m < 512; ++m) {             // m=0 term has ramp=0
            int p = (m * j) & 511;                  // exact (m*j) mod 512
            float ang = (float)(2.0 * M_PI / 512.0) * (float)p;
            int mm = m < 512 - m ? m : 512 - m;
            float ramp = 2.0f * (float)mm * (1.0f / 512.0f);
            s += ramp * cosf(ang);
        }
        s *= (1.0f / 512.0f);
        s *= (float)(M_PI / (double)VV);            // fold backprojection scale
        ws[j] = s;
        ws[j + 512] = s;                            // h_ext[j+512] == h[j]
    }
    if (j < VV) {
        float th = (float)((double)j * M_PI / 180.0);
        float c = cosf(th), sn = sinf(th);
        ws[1024 + j] = c;
        ws[1024 + 180 + j] = sn;
        ws[1408 + 2 * j] = c;
        ws[1408 + 2 * j + 1] = sn;
    }
}

// ---------------------------------------------------------------------------
// Kernel A2: shifted-quad impulse table. h4[x] = (he[x],he[x-1],he[x-2],he[x-3])
// so the conv kernel reads 4 tap-shifts with ONE ds_read_b128 instead of 4 b32.
// Only launched on the pair (table) path.
// ---------------------------------------------------------------------------
__global__ void precompute_h4_kernel(float* __restrict__ ws) {
    int x = blockIdx.x * blockDim.x + threadIdx.x;  // 0..1023
    if (x < 1024) {
        float4 h4;
        h4.x = ws[x];
        h4.y = ws[(x - 1) & 1023];   // h_ext is 512-periodic, duplicated -> &1023 ok
        h4.z = ws[(x - 2) & 1023];
        h4.w = ws[(x - 3) & 1023];
        *(float4*)(ws + H4_OFF + 4 * x) = h4;
    }
}

// ---------------------------------------------------------------------------
// Kernel B (pair path): ramp-filter convolution; epilogue writes the padded
// fp16 coefficient table in pk-SPLIT PAIRED layout:
//   tab[slice][p][cx] = uint2( half2(f0_p, f0_{p+90}), half2(d_p, d_{p+90}) )
// f0 = filtered value at floor cell, d = fp16-rounded forward difference:
// backprojection interpolates value = f0 + frac*d (no cancellation).
// Each conv block handles one angle v and writes its (f0,d) into ushort lanes
// {0,2} (v<90) or {1,3} (v>=90) of each 8B entry.
// OCCUPANCY: 256 threads / 4 waves x 4 rows (was 128/2x8 -> 1.4 waves/SIMD,
// latency-exposed). Per-output FMA order unchanged (bitwise-same results).
// ---------------------------------------------------------------------------
__global__ __launch_bounds__(256) void conv_table_kernel(const float* __restrict__ sino,
                                                         const float* __restrict__ ws,
                                                         unsigned int* __restrict__ table) {
    __shared__ float rows_s[16 * 512];   // 32 KiB
    __shared__ float4 h4_s[1024];        // 16 KiB
    int t = threadIdx.x;
    int blk = blockIdx.x;               // 0..719
    int bv = blk >> 1;                  // b*180 + v
    int half = blk & 1;                 // which 16 of the 32 r's
    int b = bv / 180;
    int v = bv - b * 180;

    const float4* src4 = (const float4*)(sino + (((size_t)bv * 32) + (size_t)half * 16) * 512);
    float4* rows4 = (float4*)rows_s;
    for (int i = t; i < 2048; i += 256) rows4[i] = src4[i];
    const float4* h4g = (const float4*)(ws + H4_OFF);
    for (int i = t; i < 1024; i += 256) h4_s[i] = h4g[i];
    __syncthreads();

    int wave = t >> 6;
    int lane = t & 63;
    int row0 = wave * 4;                // 4 rows per wave (4 waves x 4 = 16)

    float acc[4][8];
#pragma unroll
    for (int j = 0; j < 4; ++j)
#pragma unroll
        for (int i = 0; i < 8; ++i) acc[j][i] = 0.f;

    for (int k = 0; k < 512; k += 4) {
        float4 rv[4];
#pragma unroll
        for (int j = 0; j < 4; ++j)
            rv[j] = *(const float4*)&rows_s[(row0 + j) * 512 + k];
        float4 hq[8];
#pragma unroll
        for (int i = 0; i < 8; ++i)
            hq[i] = h4_s[lane - k + 512 + 64 * i];   // .x=h[A], .y=h[A-1], .z=h[A-2], .w=h[A-3]
#pragma unroll
        for (int j = 0; j < 4; ++j) {
#pragma unroll
            for (int i = 0; i < 8; ++i) {
                float a = acc[j][i];
                a = fmaf(rv[j].x, hq[i].x, a);   // u=0
                a = fmaf(rv[j].y, hq[i].y, a);   // u=1
                a = fmaf(rv[j].z, hq[i].z, a);   // u=2
                a = fmaf(rv[j].w, hq[i].w, a);   // u=3
                acc[j][i] = a;
            }
        }
    }

    // Epilogue: round-trip filtered rows through LDS, emit padded fp16 entries.
    __syncthreads();
#pragma unroll
    for (int j = 0; j < 4; ++j)
#pragma unroll
        for (int i = 0; i < 8; ++i)
            rows_s[(row0 + j) * 512 + lane + 64 * i] = acc[j][i];
    __syncthreads();

    int p = (v < 90) ? v : v - 90;
    int sh = (v < 90) ? 0 : 1;          // ushort lane within each half2 word
    for (int jj = 0; jj < 16; ++jj) {
        const float* fr = rows_s + jj * 512;
        int slice = b * 32 + half * 16 + jj;
        unsigned short* trow = (unsigned short*)(table + (((size_t)slice * 90 + p) * PW) * 2);
        for (int cx = t; cx < PW; cx += 256) {
            int s0 = cx - PADL;
            int i0 = min(max(s0, 0), 511);
            int i1 = min(max(s0 + 1, 0), 511);
            float f0 = fr[i0];
            float f1 = fr[i1];
            __half h0 = __float2half_rn(f0);
            __half h1 = __float2half_rn(f1);
            // slope from ROUNDED endpoints: lerp between stored fp16 endpoints.
            __half hd = __float2half_rn(__half2float(h1) - __half2float(h0));
            trow[(size_t)cx * 4 + sh]     = __half_as_ushort(h0);   // f0 word
            trow[(size_t)cx * 4 + 2 + sh] = __half_as_ushort(hd);   // d word
        }
    }
}

// ---------------------------------------------------------------------------
// Kernel C (pair path): orbit backprojection - fp16 8B-entry table (zero bank
// conflicts, LDS bytes halved: R2-measured) + pk-f32 accumulate (R4-measured
// clean). Construction rules from the 7-round bisection:
//   * unpack ONLY via __half22float2 (R2-clean); NEVER f16x2/fpext/asm (spill)
//   * coords/floors R2-verbatim (independent per-j recompute, floorf+sub)
//   * accumulators f32x2 partials A/M/B/C (R4-clean), merged in epilogue
// grid = (32 strips, 64 slices), block = 256. Each ds_read_b64 of
// (f0_v,f0_w | d_v,d_w) serves TWO pixel-angle samples via ONE v_pk_fma_f32.
// Mirror reuses floor: floor(-1-u) = -2-floor(u), frac' = 1-frac (exact).
// ---------------------------------------------------------------------------
__global__ __launch_bounds__(256, 6) void backproj_pair_kernel(const uint2* __restrict__ tab,
                                                               const float2* __restrict__ trigp,
                                                               float* __restrict__ out) {
    __shared__ uint2 pbuf[CHP * PW];    // 11584 B
    __shared__ float2 trig_s[90];
    int t = threadIdx.x;
    int slice = blockIdx.y;             // b*32 + r
    int strip = blockIdx.x;             // 0..31
    int y0 = strip * SH3;               // rep-row offset in [0,256)
    const uint2* tslice = tab + (size_t)slice * (90 * PW);

    for (int i = t; i < 90; i += 256) trig_s[i] = trigp[i];

    float xc = (float)t + 0.5f;         // rep px = 256+t  ->  xc = px-255.5

    // Packed partials: A<-gather(ua), M<-gather(uma), B<-gather(ub),
    // C<-gather(umb). Component .x = @v contribution, .y = @v+90.
    f32x2 accA[SH3], accM[SH3], accB[SH3], accC[SH3];
#pragma unroll
    for (int j = 0; j < SH3; ++j) {
        accA[j] = mk2(0.f, 0.f); accM[j] = mk2(0.f, 0.f);
        accB[j] = mk2(0.f, 0.f); accC[j] = mk2(0.f, 0.f);
    }

    for (int chunk = 0; chunk < NCHP; ++chunk) {
        __syncthreads();                // previous chunk consumed (covers trig_s on chunk 0)
        const float4* src = (const float4*)(tslice + chunk * (CHP * PW));
        float4* dst = (float4*)pbuf;
        for (int i = t; i < (CHP * PW) / 2; i += 256) dst[i] = src[i];
        __syncthreads();
#pragma unroll
        for (int pa = 0; pa < CHP; ++pa) {
            float2 cs = trig_s[chunk * CHP + pa];
            const uint2* pb = pbuf + pa * PW + TCEN;
#pragma unroll
            for (int j = 0; j < SH3; ++j) {
                float ycj = (float)(y0 + j) + 0.5f;
                float ysm  = fmaf(ycj, cs.y, -0.5f);    // y*sin - 0.5
                float yccm = fmaf(-ycj, cs.x, -0.5f);   // -y*cos - 0.5
                float ua  = fmaf(xc, cs.x, ysm);        // u( a) = x c + y s - .5
                float ub  = fmaf(xc, cs.y, yccm);       // u( b) = x s - y c - .5
                float fla = floorf(ua);
                float flb = floorf(ub);
                int ma  = (int)fla;
                int mb  = (int)flb;
                float ra = ua - fla;                    // frac in [0,1)
                float rb = ub - flb;
                int mma = -2 - ma;                      // floor(-1-ua), exact
                int mmb = -2 - mb;
                float rma = 1.0f - ra;
                float rmb = 1.0f - rb;
                uint2 qa  = pb[ma];
                uint2 qma = pb[mma];
                uint2 qb  = pb[mb];
                uint2 qmb = pb[mmb];
                accA[j] += sample2(ra,  qa);    // (P0@v,        P1@v+90)
                accM[j] += sample2(rma, qma);   // (P2@v,        P3@v+90)
                accB[j] += sample2(rb,  qb);    // (P1@v,        P2@v+90)
                accC[j] += sample2(rmb, qmb);   // (P3@v,        P0@v+90)
            }
        }
    }

    // Merge packed partials into the 4 orbit pixels:
    //   P0 = A.x + C.y ; P1 = A.y + B.x ; P2 = M.x + B.y ; P3 = M.y + C.x
    // Orbit writes. P0/P2 are row-coalesced; P1/P3 are per-lane 32B row
    // segments (columns of the orbit) - accepted write amplification.
    int px = 256 + t;
    size_t sbase = (size_t)slice * (512 * 512);
#pragma unroll
    for (int j = 0; j < SH3; ++j) {
        int py = 256 + y0 + j;
        float v0 = accA[j].x + accC[j].y;
        float v1 = accA[j].y + accB[j].x;
        float v2 = accM[j].x + accB[j].y;
        float v3 = accM[j].y + accC[j].x;
        out[sbase + (size_t)py * 512 + px]                   = v0 > 0.f ? v0 : 0.f;  // (x=px,    y=py)
        out[sbase + (size_t)px * 512 + (511 - py)]           = v1 > 0.f ? v1 : 0.f;  // (x=511-py,y=px)
        out[sbase + (size_t)(511 - py) * 512 + (511 - px)]   = v2 > 0.f ? v2 : 0.f;  // (x=511-px,y=511-py)
        out[sbase + (size_t)(511 - px) * 512 + py]           = v3 > 0.f ? v3 : 0.f;  // (x=py,    y=511-px)
    }
}

// ===========================================================================
// Fallback path (round-3 kernels) - used only if ws_size can't hold the table.
// ===========================================================================
__global__ __launch_bounds__(128) void conv_kernel(const float* __restrict__ sino,
                                                   const float* __restrict__ ws,
                                                   float* __restrict__ filt) {
    __shared__ float rows_s[16 * 512];
    __shared__ float h_s[1024];
    int t = threadIdx.x;
    int blk = blockIdx.x;
    int bv = blk >> 1;
    int half = blk & 1;
    int b = bv / 180;
    int v = bv - b * 180;

    const float4* src4 = (const float4*)(sino + (((size_t)bv * 32) + (size_t)half * 16) * 512);
    float4* rows4 = (float4*)rows_s;
    for (int i = t; i < 2048; i += 128) rows4[i] = src4[i];
    for (int i = t; i < 1024; i += 128) h_s[i] = ws[i];
    __syncthreads();

    int wave = t >> 6;
    int lane = t & 63;
    int row0 = wave * 8;

    float acc[8][8];
#pragma unroll
    for (int j = 0; j < 8; ++j)
#pragma unroll
        for (int i = 0; i < 8; ++i) acc[j][i] = 0.f;

    for (int k = 0; k < 512; k += 4) {
        float4 rv[8];
#pragma unroll
        for (int j = 0; j < 8; ++j)
            rv[j] = *(const float4*)&rows_s[(row0 + j) * 512 + k];
#pragma unroll
        for (int u = 0; u < 4; ++u) {
            float hv[8];
            int base = lane - (k + u) + 512;
#pragma unroll
            for (int i = 0; i < 8; ++i) hv[i] = h_s[base + 64 * i];
#pragma unroll
            for (int j = 0; j < 8; ++j) {
                float rj = (u == 0) ? rv[j].x : (u == 1) ? rv[j].y : (u == 2) ? rv[j].z : rv[j].w;
#pragma unroll
                for (int i = 0; i < 8; ++i) acc[j][i] = fmaf(rj, hv[i], acc[j][i]);
            }
        }
    }

#pragma unroll
    for (int j = 0; j < 8; ++j) {
        int r = half * 16 + row0 + j;
        float* dst = filt + (((size_t)b * 32 + r) * 180 + v) * 512;
#pragma unroll
        for (int i = 0; i < 8; ++i) dst[lane + 64 * i] = acc[j][i];
    }
}

__global__ __launch_bounds__(256) void backproj_kernel(const float* __restrict__ filt,
                                                       const float* __restrict__ trig,
                                                       float* __restrict__ out) {
    __shared__ float2 pbuf[CH2][PW];
    __shared__ float trig_s[360];
    int t = threadIdx.x;
    int slice = blockIdx.y;
    int strip = blockIdx.x;
    int y0 = strip * SH;
    int lane = t & 63;
    int wave = t >> 6;
    int x0 = wave * 128;
    const float* slice_p = filt + (size_t)slice * (180 * 512);

    for (int i = t; i < 360; i += 256) trig_s[i] = trig[i];

    float xc0 = (float)(x0 + lane) - 255.5f;
    float xc1 = xc0 + 64.0f;
    float yb0 = (float)y0 - 255.5f;

    float acc[2][SH];
#pragma unroll
    for (int g = 0; g < 2; ++g)
#pragma unroll
        for (int j = 0; j < SH; ++j) acc[g][j] = 0.f;

    for (int chunk = 0; chunk < NCHUNK2; ++chunk) {
        int v0 = chunk * CH2;
        __syncthreads();
#pragma unroll 1
        for (int a = 0; a < CH2; ++a) {
            const float* prow = slice_p + (v0 + a) * 512;
            for (int cx = t; cx < PW; cx += 256) {
                int s0 = cx - PADL;
                int i0 = min(max(s0, 0), 511);
                int i1 = min(max(s0 + 1, 0), 511);
                float f0 = prow[i0];
                float d = prow[i1] - f0;
                float m = (float)(cx - TCEN);
                pbuf[a][cx] = make_float2(fmaf(-m, d, f0), d);
            }
        }
        __syncthreads();
#pragma unroll 1
        for (int a = 0; a < CH2; ++a) {
            float cth = trig_s[v0 + a];
            float sth = trig_s[180 + v0 + a];
            float ybase = fmaf(yb0, sth, 255.5f + (float)PADL - (float)TCEN);
            float t0 = fmaf(xc0, cth, ybase);
            float t1 = fmaf(xc1, cth, ybase);
            const char* pb = (const char*)pbuf;
            int aoff = a * (PW * 8) + TCEN * 8;
#pragma unroll
            for (int j = 0; j < SH; ++j) {
                int m0 = (int)floorf(t0);
                float2 g0 = *(const float2*)(pb + (m0 * 8 + aoff));
                acc[0][j] = fmaf(t0, g0.y, acc[0][j]) + g0.x;
                t0 += sth;

                int m1 = (int)floorf(t1);
                float2 g1 = *(const float2*)(pb + (m1 * 8 + aoff));
                acc[1][j] = fmaf(t1, g1.y, acc[1][j]) + g1.x;
                t1 += sth;
            }
        }
    }

    size_t obase = ((size_t)slice * 512 + (size_t)y0) * 512;
#pragma unroll
    for (int j = 0; j < SH; ++j) {
        float v0o = acc[0][j];
        float v1o = acc[1][j];
        out[obase + (size_t)j * 512 + x0 + lane] = v0o > 0.f ? v0o : 0.f;
        out[obase + (size_t)j * 512 + x0 + 64 + lane] = v1o > 0.f ? v1o : 0.f;
    }
}

extern "C" void kernel_launch(void* const* d_in, const int* in_sizes, int n_in,
                              void* d_out, int out_size, void* d_ws, size_t ws_size,
                              hipStream_t stream) {
    const float* sino = (const float*)d_in[0];
    float* out = (float*)d_out;
    float* ws = (float*)d_ws;

    size_t tableWords = (size_t)64 * 90 * PW * 2;              // uint32 count (8.34M)
    size_t needed = ((size_t)TAB_OFF + tableWords) * 4;        // ~33.4 MB

    precompute_kernel<<<2, 256, 0, stream>>>(ws);
    if (ws_size >= needed) {
        unsigned int* table = (unsigned int*)(ws + TAB_OFF);
        precompute_h4_kernel<<<4, 256, 0, stream>>>(ws);
        conv_table_kernel<<<720, 256, 0, stream>>>(sino, ws, table);
        backproj_pair_kernel<<<dim3(32, 64), 256, 0, stream>>>((const uint2*)table,
                                                               (const float2*)(ws + 1408), out);
    } else {
        float* filt = ws + FILT_OFF;
        conv_kernel<<<720, 128, 0, stream>>>(sino, ws, filt);
        backproj_kernel<<<dim3(32, 64), 256, 0, stream>>>(filt, ws + 1024, out);
    }
}

// Round 9
// 618.292 us; speedup vs baseline: 1.7794x; 1.7794x over previous
//
#include <hip/hip_runtime.h>
#include <hip/hip_fp16.h>
#include <math.h>

#ifndef M_PI
#define M_PI 3.14159265358979323846
#endif

// Problem constants
#define BB 2
#define VV 180
#define RR 32
#define CC 512
#define NPIX 512

#define PADL 106     // left padding of t-range
#define PW 724       // padded width: t_real in [-106, 617]
#define TCEN 362     // recentering offset for table indexing

// pair-orbit backprojection tiling
#define SH3 8        // rep-rows per block
#define CHP 1        // angle-PAIRS per LDS chunk (1 -> 11.6KB pbuf -> 8 blocks/CU)
#define NCHP 90      // 90 * 1 = 90 pairs = 180 angles

// fallback tiling (round-3 kernels)
#define SH 16
#define CH2 6
#define NCHUNK2 30

// ws layout (floats):
//   [0,1024)      h_ext (impulse response, duplicated, scaled by pi/V)
//   [1024,1384)   legacy trig: cos[180] | sin[180]          (fallback path)
//   [1408,1768)   trig2: interleaved (cos,sin) float2[180]  (pair path uses first 90)
//   [2048,6144)   h4 quad table: float4 h4[x] = (h[x],h[x-1],h[x-2],h[x-3])
//   [6144,...)    pair path: fp32 table [64 slices][90 pairs][724] float4 = 66.7 MB
//                   entry = (c_v, c_w, d_v, d_w)  -- pk-friendly grouping
//   fallback:     filt at [2048,...) (h4 NOT written in fallback mode)
#define H4_OFF 2048
#define TAB_OFF 6144
#define FILT_OFF 2048

typedef float f32x2 __attribute__((ext_vector_type(2)));

static __device__ __forceinline__ f32x2 mk2(float a, float b) {
    f32x2 r; r.x = a; r.y = b; return r;
}

// ---------------------------------------------------------------------------
// Kernel A: ramp-filter impulse response h[k] (scaled by pi/V) + angle tables.
// ---------------------------------------------------------------------------
__global__ void precompute_kernel(float* __restrict__ ws) {
    int j = blockIdx.x * blockDim.x + threadIdx.x;  // 0..511
    if (j < 512) {
        float s = 0.f;
        for (int m = 1; m < 512; ++m) {             // m=0 term has ramp=0
            int p = (m * j) & 511;                  // exact (m*j) mod 512
            float ang = (float)(2.0 * M_PI / 512.0) * (float)p;
            int mm = m < 512 - m ? m : 512 - m;
            float ramp = 2.0f * (float)mm * (1.0f / 512.0f);
            s += ramp * cosf(ang);
        }
        s *= (1.0f / 512.0f);
        s *= (float)(M_PI / (double)VV);            // fold backprojection scale
        ws[j] = s;
        ws[j + 512] = s;                            // h_ext[j+512] == h[j]
    }
    if (j < VV) {
        float th = (float)((double)j * M_PI / 180.0);
        float c = cosf(th), sn = sinf(th);
        ws[1024 + j] = c;
        ws[1024 + 180 + j] = sn;
        ws[1408 + 2 * j] = c;
        ws[1408 + 2 * j + 1] = sn;
    }
}

// ---------------------------------------------------------------------------
// Kernel A2: shifted-quad impulse table. h4[x] = (he[x],he[x-1],he[x-2],he[x-3])
// so the conv kernel reads 4 tap-shifts with ONE ds_read_b128 instead of 4 b32.
// Only launched on the pair (table) path.
// ---------------------------------------------------------------------------
__global__ void precompute_h4_kernel(float* __restrict__ ws) {
    int x = blockIdx.x * blockDim.x + threadIdx.x;  // 0..1023
    if (x < 1024) {
        float4 h4;
        h4.x = ws[x];
        h4.y = ws[(x - 1) & 1023];   // h_ext is 512-periodic, duplicated -> &1023 ok
        h4.z = ws[(x - 2) & 1023];
        h4.w = ws[(x - 3) & 1023];
        *(float4*)(ws + H4_OFF + 4 * x) = h4;
    }
}

// ---------------------------------------------------------------------------
// Kernel B (pair path): ramp-filter convolution; epilogue writes the padded
// fp32 coefficient table in pk-friendly PAIRED layout:
//   tab[slice][p][cx] = (c_p, c_{p+90}, d_p, d_{p+90})
// with c = f0 - (cx-TCEN)*d so that sample = c + u*d for raw coordinate u.
// Each conv block handles one angle v and writes its (c,d) into words {0,2}
// (v<90) or {1,3} (v>=90) of each 16B entry.  (R4-verbatim, proven clean.)
// ---------------------------------------------------------------------------
__global__ __launch_bounds__(128) void conv_table_kernel(const float* __restrict__ sino,
                                                         const float* __restrict__ ws,
                                                         float* __restrict__ table) {
    __shared__ float rows_s[16 * 512];   // 32 KiB
    __shared__ float4 h4_s[1024];        // 16 KiB
    int t = threadIdx.x;
    int blk = blockIdx.x;               // 0..719
    int bv = blk >> 1;                  // b*180 + v
    int half = blk & 1;                 // which 16 of the 32 r's
    int b = bv / 180;
    int v = bv - b * 180;

    const float4* src4 = (const float4*)(sino + (((size_t)bv * 32) + (size_t)half * 16) * 512);
    float4* rows4 = (float4*)rows_s;
    for (int i = t; i < 2048; i += 128) rows4[i] = src4[i];
    const float4* h4g = (const float4*)(ws + H4_OFF);
    for (int i = t; i < 1024; i += 128) h4_s[i] = h4g[i];
    __syncthreads();

    int wave = t >> 6;
    int lane = t & 63;
    int row0 = wave * 8;

    float acc[8][8];
#pragma unroll
    for (int j = 0; j < 8; ++j)
#pragma unroll
        for (int i = 0; i < 8; ++i) acc[j][i] = 0.f;

    for (int k = 0; k < 512; k += 4) {
        float4 rv[8];
#pragma unroll
        for (int j = 0; j < 8; ++j)
            rv[j] = *(const float4*)&rows_s[(row0 + j) * 512 + k];
        float4 hq[8];
#pragma unroll
        for (int i = 0; i < 8; ++i)
            hq[i] = h4_s[lane - k + 512 + 64 * i];   // .x=h[A], .y=h[A-1], .z=h[A-2], .w=h[A-3]
#pragma unroll
        for (int j = 0; j < 8; ++j) {
#pragma unroll
            for (int i = 0; i < 8; ++i) {
                float a = acc[j][i];
                a = fmaf(rv[j].x, hq[i].x, a);   // u=0
                a = fmaf(rv[j].y, hq[i].y, a);   // u=1
                a = fmaf(rv[j].z, hq[i].z, a);   // u=2
                a = fmaf(rv[j].w, hq[i].w, a);   // u=3
                acc[j][i] = a;
            }
        }
    }

    // Epilogue: round-trip filtered rows through LDS, emit padded fp32 (c,d).
    __syncthreads();
#pragma unroll
    for (int j = 0; j < 8; ++j)
#pragma unroll
        for (int i = 0; i < 8; ++i)
            rows_s[(row0 + j) * 512 + lane + 64 * i] = acc[j][i];
    __syncthreads();

    int p = (v < 90) ? v : v - 90;
    int word = (v < 90) ? 0 : 1;
    for (int jj = 0; jj < 16; ++jj) {
        const float* fr = rows_s + jj * 512;
        int slice = b * 32 + half * 16 + jj;
        float* trow = table + (((size_t)slice * 90 + p) * PW) * 4 + word;
        for (int cx = t; cx < PW; cx += 128) {
            int s0 = cx - PADL;
            int i0 = min(max(s0, 0), 511);
            int i1 = min(max(s0 + 1, 0), 511);
            float f0 = fr[i0];
            float d = fr[i1] - f0;
            float m = (float)(cx - TCEN);
            trow[(size_t)cx * 4]     = fmaf(-m, d, f0);   // c
            trow[(size_t)cx * 4 + 2] = d;                 // d
        }
    }
}

// ---------------------------------------------------------------------------
// Kernel C (pair path): orbit backprojection, packed-f32 edition (R4-verbatim
// dataflow -- the only proven-clean fast form across 8 rounds) with ONE change:
// CHP=1 halves the pbuf to 11.6 KB so residency rises from 6 to 8 blocks/CU
// (thread-capped), lifting occupancy 47% -> ~75% to better fill the LDS pipe.
// grid = (32 strips, 64 slices), block = 256. Each ds_read_b128 of
// (c_v,c_w,d_v,d_w) serves TWO pixel-angle samples (pair-orbit sharing);
// arithmetic is ONE v_pk_fma_f32 + ONE v_pk_add_f32 per gather.
// Construction rules (7-round bisection): independent per-j iters, f32-only
// register math, __float2int_rd index, NO f16 ops / fractf / serial chain /
// inline asm (each of those scratch-spilled: 3-8 GB HBM signatures).
// ---------------------------------------------------------------------------
__global__ __launch_bounds__(256, 4) void backproj_pair_kernel(const float4* __restrict__ tab,
                                                               const float2* __restrict__ trigp,
                                                               float* __restrict__ out) {
    __shared__ float4 pbuf[CHP * PW];   // 11584 B -> 8 blocks/CU (thread-capped)
    __shared__ float2 trig_s[90];
    int t = threadIdx.x;
    int slice = blockIdx.y;             // b*32 + r
    int strip = blockIdx.x;             // 0..31
    int y0 = strip * SH3;               // rep-row offset in [0,256)
    const float4* tslice = tab + (size_t)slice * (90 * PW);

    for (int i = t; i < 90; i += 256) trig_s[i] = trigp[i];

    float xc = (float)t + 0.5f;         // rep px = 256+t  ->  xc = px-255.5

    // Packed partials: A<-gather(ua), M<-gather(uma), B<-gather(ub),
    // C<-gather(umb). Component .x = @v contribution, .y = @v+90.
    f32x2 accA[SH3], accM[SH3], accB[SH3], accC[SH3];
#pragma unroll
    for (int j = 0; j < SH3; ++j) {
        accA[j] = mk2(0.f, 0.f); accM[j] = mk2(0.f, 0.f);
        accB[j] = mk2(0.f, 0.f); accC[j] = mk2(0.f, 0.f);
    }

    for (int chunk = 0; chunk < NCHP; ++chunk) {
        __syncthreads();                // previous chunk consumed (covers trig_s on chunk 0)
        const float4* src = tslice + chunk * (CHP * PW);
        for (int i = t; i < CHP * PW; i += 256) pbuf[i] = src[i];
        __syncthreads();
        {
            float2 cs = trig_s[chunk];
            const float4* pb = pbuf + TCEN;
#pragma unroll
            for (int j = 0; j < SH3; ++j) {
                float ycj = (float)(y0 + j) + 0.5f;
                float ua  = fmaf(xc, cs.x, fmaf(ycj, cs.y, -0.5f));   // x c + y s - .5
                float ub  = fmaf(xc, cs.y, fmaf(-ycj, cs.x, -0.5f));  // x s - y c - .5
                int ma = __float2int_rd(ua);                // v_cvt_flr_i32_f32
                int mb = __float2int_rd(ub);
                float uma = -1.0f - ua;                     // u(-a); floor = -2-ma
                float umb = -1.0f - ub;
                float4 qa = pb[ma];
                float4 qm = pb[-2 - ma];
                float4 qb = pb[mb];
                float4 qn = pb[-2 - mb];
                // sample pair = (c_v,c_w) + u*(d_v,d_w): v_pk_fma_f32 + v_pk_add_f32
                accA[j] += __builtin_elementwise_fma(mk2(ua,  ua),  mk2(qa.z, qa.w), mk2(qa.x, qa.y));
                accM[j] += __builtin_elementwise_fma(mk2(uma, uma), mk2(qm.z, qm.w), mk2(qm.x, qm.y));
                accB[j] += __builtin_elementwise_fma(mk2(ub,  ub),  mk2(qb.z, qb.w), mk2(qb.x, qb.y));
                accC[j] += __builtin_elementwise_fma(mk2(umb, umb), mk2(qn.z, qn.w), mk2(qn.x, qn.y));
            }
        }
    }

    // Merge packed partials into the 4 orbit pixels:
    //   P0 = A.x + C.y ; P1 = A.y + B.x ; P2 = M.x + B.y ; P3 = M.y + C.x
    // Orbit writes. P0/P2 are row-coalesced; P1/P3 are per-lane 32B row
    // segments (columns of the orbit) - accepted write amplification.
    int px = 256 + t;
    size_t sbase = (size_t)slice * (512 * 512);
#pragma unroll
    for (int j = 0; j < SH3; ++j) {
        int py = 256 + y0 + j;
        float v0 = accA[j].x + accC[j].y;
        float v1 = accA[j].y + accB[j].x;
        float v2 = accM[j].x + accB[j].y;
        float v3 = accM[j].y + accC[j].x;
        out[sbase + (size_t)py * 512 + px]                   = v0 > 0.f ? v0 : 0.f;  // (x=px,    y=py)
        out[sbase + (size_t)px * 512 + (511 - py)]           = v1 > 0.f ? v1 : 0.f;  // (x=511-py,y=px)
        out[sbase + (size_t)(511 - py) * 512 + (511 - px)]   = v2 > 0.f ? v2 : 0.f;  // (x=511-px,y=511-py)
        out[sbase + (size_t)(511 - px) * 512 + py]           = v3 > 0.f ? v3 : 0.f;  // (x=py,    y=511-px)
    }
}

// ===========================================================================
// Fallback path (round-3 kernels) - used only if ws_size can't hold the table.
// ===========================================================================
__global__ __launch_bounds__(128) void conv_kernel(const float* __restrict__ sino,
                                                   const float* __restrict__ ws,
                                                   float* __restrict__ filt) {
    __shared__ float rows_s[16 * 512];
    __shared__ float h_s[1024];
    int t = threadIdx.x;
    int blk = blockIdx.x;
    int bv = blk >> 1;
    int half = blk & 1;
    int b = bv / 180;
    int v = bv - b * 180;

    const float4* src4 = (const float4*)(sino + (((size_t)bv * 32) + (size_t)half * 16) * 512);
    float4* rows4 = (float4*)rows_s;
    for (int i = t; i < 2048; i += 128) rows4[i] = src4[i];
    for (int i = t; i < 1024; i += 128) h_s[i] = ws[i];
    __syncthreads();

    int wave = t >> 6;
    int lane = t & 63;
    int row0 = wave * 8;

    float acc[8][8];
#pragma unroll
    for (int j = 0; j < 8; ++j)
#pragma unroll
        for (int i = 0; i < 8; ++i) acc[j][i] = 0.f;

    for (int k = 0; k < 512; k += 4) {
        float4 rv[8];
#pragma unroll
        for (int j = 0; j < 8; ++j)
            rv[j] = *(const float4*)&rows_s[(row0 + j) * 512 + k];
#pragma unroll
        for (int u = 0; u < 4; ++u) {
            float hv[8];
            int base = lane - (k + u) + 512;
#pragma unroll
            for (int i = 0; i < 8; ++i) hv[i] = h_s[base + 64 * i];
#pragma unroll
            for (int j = 0; j < 8; ++j) {
                float rj = (u == 0) ? rv[j].x : (u == 1) ? rv[j].y : (u == 2) ? rv[j].z : rv[j].w;
#pragma unroll
                for (int i = 0; i < 8; ++i) acc[j][i] = fmaf(rj, hv[i], acc[j][i]);
            }
        }
    }

#pragma unroll
    for (int j = 0; j < 8; ++j) {
        int r = half * 16 + row0 + j;
        float* dst = filt + (((size_t)b * 32 + r) * 180 + v) * 512;
#pragma unroll
        for (int i = 0; i < 8; ++i) dst[lane + 64 * i] = acc[j][i];
    }
}

__global__ __launch_bounds__(256) void backproj_kernel(const float* __restrict__ filt,
                                                       const float* __restrict__ trig,
                                                       float* __restrict__ out) {
    __shared__ float2 pbuf[CH2][PW];
    __shared__ float trig_s[360];
    int t = threadIdx.x;
    int slice = blockIdx.y;
    int strip = blockIdx.x;
    int y0 = strip * SH;
    int lane = t & 63;
    int wave = t >> 6;
    int x0 = wave * 128;
    const float* slice_p = filt + (size_t)slice * (180 * 512);

    for (int i = t; i < 360; i += 256) trig_s[i] = trig[i];

    float xc0 = (float)(x0 + lane) - 255.5f;
    float xc1 = xc0 + 64.0f;
    float yb0 = (float)y0 - 255.5f;

    float acc[2][SH];
#pragma unroll
    for (int g = 0; g < 2; ++g)
#pragma unroll
        for (int j = 0; j < SH; ++j) acc[g][j] = 0.f;

    for (int chunk = 0; chunk < NCHUNK2; ++chunk) {
        int v0 = chunk * CH2;
        __syncthreads();
#pragma unroll 1
        for (int a = 0; a < CH2; ++a) {
            const float* prow = slice_p + (v0 + a) * 512;
            for (int cx = t; cx < PW; cx += 256) {
                int s0 = cx - PADL;
                int i0 = min(max(s0, 0), 511);
                int i1 = min(max(s0 + 1, 0), 511);
                float f0 = prow[i0];
                float d = prow[i1] - f0;
                float m = (float)(cx - TCEN);
                pbuf[a][cx] = make_float2(fmaf(-m, d, f0), d);
            }
        }
        __syncthreads();
#pragma unroll 1
        for (int a = 0; a < CH2; ++a) {
            float cth = trig_s[v0 + a];
            float sth = trig_s[180 + v0 + a];
            float ybase = fmaf(yb0, sth, 255.5f + (float)PADL - (float)TCEN);
            float t0 = fmaf(xc0, cth, ybase);
            float t1 = fmaf(xc1, cth, ybase);
            const char* pb = (const char*)pbuf;
            int aoff = a * (PW * 8) + TCEN * 8;
#pragma unroll
            for (int j = 0; j < SH; ++j) {
                int m0 = (int)floorf(t0);
                float2 g0 = *(const float2*)(pb + (m0 * 8 + aoff));
                acc[0][j] = fmaf(t0, g0.y, acc[0][j]) + g0.x;
                t0 += sth;

                int m1 = (int)floorf(t1);
                float2 g1 = *(const float2*)(pb + (m1 * 8 + aoff));
                acc[1][j] = fmaf(t1, g1.y, acc[1][j]) + g1.x;
                t1 += sth;
            }
        }
    }

    size_t obase = ((size_t)slice * 512 + (size_t)y0) * 512;
#pragma unroll
    for (int j = 0; j < SH; ++j) {
        float v0o = acc[0][j];
        float v1o = acc[1][j];
        out[obase + (size_t)j * 512 + x0 + lane] = v0o > 0.f ? v0o : 0.f;
        out[obase + (size_t)j * 512 + x0 + 64 + lane] = v1o > 0.f ? v1o : 0.f;
    }
}

extern "C" void kernel_launch(void* const* d_in, const int* in_sizes, int n_in,
                              void* d_out, int out_size, void* d_ws, size_t ws_size,
                              hipStream_t stream) {
    const float* sino = (const float*)d_in[0];
    float* out = (float*)d_out;
    float* ws = (float*)d_ws;

    size_t tableFloats = (size_t)64 * 90 * PW * 4;             // 16.68M floats
    size_t needed = ((size_t)TAB_OFF + tableFloats) * 4;       // ~66.7 MB

    precompute_kernel<<<2, 256, 0, stream>>>(ws);
    if (ws_size >= needed) {
        float* table = ws + TAB_OFF;
        precompute_h4_kernel<<<4, 256, 0, stream>>>(ws);
        conv_table_kernel<<<720, 128, 0, stream>>>(sino, ws, table);
        backproj_pair_kernel<<<dim3(32, 64), 256, 0, stream>>>((const float4*)table,
                                                               (const float2*)(ws + 1408), out);
    } else {
        float* filt = ws + FILT_OFF;
        conv_kernel<<<720, 128, 0, stream>>>(sino, ws, filt);
        backproj_kernel<<<dim3(32, 64), 256, 0, stream>>>(filt, ws + 1024, out);
    }
}

// Round 10
// 592.876 us; speedup vs baseline: 1.8557x; 1.0429x over previous
//
#include <hip/hip_runtime.h>
#include <hip/hip_fp16.h>
#include <math.h>

#ifndef M_PI
#define M_PI 3.14159265358979323846
#endif

// Problem constants
#define BB 2
#define VV 180
#define RR 32
#define CC 512
#define NPIX 512

#define PADL 106     // left padding of t-range
#define PW 724       // padded width: t_real in [-106, 617]
#define TCEN 362     // recentering offset for table indexing

// pair-orbit backprojection tiling (R4 champion config)
#define SH3 8        // rep-rows per block
#define CHP 2        // angle-PAIRS per LDS chunk
#define NCHP 45      // 45 * 2 = 90 pairs = 180 angles

// fallback tiling (round-3 kernels)
#define SH 16
#define CH2 6
#define NCHUNK2 30

// ws layout (floats):
//   [0,1024)      h_ext (impulse response, duplicated, scaled by pi/V)
//   [1024,1384)   legacy trig: cos[180] | sin[180]          (fallback path)
//   [1408,1768)   trig2: interleaved (cos,sin) float2[180]  (pair path uses first 90)
//   [2048,6144)   h4 quad table: float4 h4[x] = (h[x],h[x-1],h[x-2],h[x-3])
//   [6144,...)    pair path: fp32 table [64 slices][90 pairs][724] float4 = 66.7 MB
//                   entry = (c_v, c_w, d_v, d_w)  -- pk-friendly grouping
//   fallback:     filt at [2048,...) (h4 NOT written in fallback mode)
#define H4_OFF 2048
#define TAB_OFF 6144
#define FILT_OFF 2048

typedef float f32x2 __attribute__((ext_vector_type(2)));

static __device__ __forceinline__ f32x2 mk2(float a, float b) {
    f32x2 r; r.x = a; r.y = b; return r;
}

// ---------------------------------------------------------------------------
// Kernel A: ramp-filter impulse response h[k] (scaled by pi/V) + angle tables.
// ---------------------------------------------------------------------------
__global__ void precompute_kernel(float* __restrict__ ws) {
    int j = blockIdx.x * blockDim.x + threadIdx.x;  // 0..511
    if (j < 512) {
        float s = 0.f;
        for (int m = 1; m < 512; ++m) {             // m=0 term has ramp=0
            int p = (m * j) & 511;                  // exact (m*j) mod 512
            float ang = (float)(2.0 * M_PI / 512.0) * (float)p;
            int mm = m < 512 - m ? m : 512 - m;
            float ramp = 2.0f * (float)mm * (1.0f / 512.0f);
            s += ramp * cosf(ang);
        }
        s *= (1.0f / 512.0f);
        s *= (float)(M_PI / (double)VV);            // fold backprojection scale
        ws[j] = s;
        ws[j + 512] = s;                            // h_ext[j+512] == h[j]
    }
    if (j < VV) {
        float th = (float)((double)j * M_PI / 180.0);
        float c = cosf(th), sn = sinf(th);
        ws[1024 + j] = c;
        ws[1024 + 180 + j] = sn;
        ws[1408 + 2 * j] = c;
        ws[1408 + 2 * j + 1] = sn;
    }
}

// ---------------------------------------------------------------------------
// Kernel A2: shifted-quad impulse table. h4[x] = (he[x],he[x-1],he[x-2],he[x-3])
// so the conv kernel reads 4 tap-shifts with ONE ds_read_b128 instead of 4 b32.
// Only launched on the pair (table) path.
// ---------------------------------------------------------------------------
__global__ void precompute_h4_kernel(float* __restrict__ ws) {
    int x = blockIdx.x * blockDim.x + threadIdx.x;  // 0..1023
    if (x < 1024) {
        float4 h4;
        h4.x = ws[x];
        h4.y = ws[(x - 1) & 1023];   // h_ext is 512-periodic, duplicated -> &1023 ok
        h4.z = ws[(x - 2) & 1023];
        h4.w = ws[(x - 3) & 1023];
        *(float4*)(ws + H4_OFF + 4 * x) = h4;
    }
}

// ---------------------------------------------------------------------------
// Kernel B (pair path): ramp-filter convolution, PACKED-ROW-PAIR edition.
// Two sino rows share the same h multiplier for every output column, so rows
// are staged INTERLEAVED in LDS (float2(r_2p[c], r_2p+1[c])): the b128
// broadcast read then yields natural f32x2 operands and each tap is ONE
// v_pk_fma_f32 (halves conv's VALU issue, the measured binder at ~154 us).
// Per-output FMA chains keep identical (k,u) order -> bitwise-same filter.
// Epilogue writes the padded fp32 table in pk-friendly PAIRED layout:
//   tab[slice][p][cx] = (c_p, c_{p+90}, d_p, d_{p+90}),  c = f0-(cx-TCEN)*d.
// Pure-f32 register math (R4-proven clean: no f16 ops / fractf / asm).
// ---------------------------------------------------------------------------
__global__ __launch_bounds__(128) void conv_table_kernel(const float* __restrict__ sino,
                                                         const float* __restrict__ ws,
                                                         float* __restrict__ table) {
    __shared__ float rows_s[16 * 512];   // 32 KiB; interleaved pair-layout in main loop
    __shared__ float4 h4_s[1024];        // 16 KiB
    int t = threadIdx.x;
    int blk = blockIdx.x;               // 0..719
    int bv = blk >> 1;                  // b*180 + v
    int half = blk & 1;                 // which 16 of the 32 r's
    int b = bv / 180;
    int v = bv - b * 180;

    const float4* src4 = (const float4*)(sino + (((size_t)bv * 32) + (size_t)half * 16) * 512);
    float4* rows4 = (float4*)rows_s;
    // Interleaved staging: pair p = rows (2p, 2p+1); col-quad q.
    //   rows4[p*256 + 2q]   = (a.x, b.x, a.y, b.y)   cols 4q, 4q+1
    //   rows4[p*256 + 2q+1] = (a.z, b.z, a.w, b.w)   cols 4q+2, 4q+3
    for (int idx = t; idx < 1024; idx += 128) {
        int p = idx >> 7;
        int q = idx & 127;
        float4 a4 = src4[(2 * p) * 128 + q];
        float4 b4 = src4[(2 * p + 1) * 128 + q];
        rows4[p * 256 + q * 2]     = make_float4(a4.x, b4.x, a4.y, b4.y);
        rows4[p * 256 + q * 2 + 1] = make_float4(a4.z, b4.z, a4.w, b4.w);
    }
    const float4* h4g = (const float4*)(ws + H4_OFF);
    for (int i = t; i < 1024; i += 128) h4_s[i] = h4g[i];
    __syncthreads();

    int wave = t >> 6;
    int lane = t & 63;
    int pr0 = wave * 4;                 // pair base: wave0 -> rows 0..7, wave1 -> 8..15

    f32x2 acc[4][8];                    // [pair][output octant]; .x=row 2p, .y=row 2p+1
#pragma unroll
    for (int p = 0; p < 4; ++p)
#pragma unroll
        for (int i = 0; i < 8; ++i) acc[p][i] = mk2(0.f, 0.f);

    for (int k = 0; k < 512; k += 4) {
        f32x2 rp[4][4];                 // [pair][tap u] packed (row2p, row2p+1) at col k+u
#pragma unroll
        for (int p = 0; p < 4; ++p) {
            float4 w0 = rows4[(pr0 + p) * 256 + (k >> 1)];
            float4 w1 = rows4[(pr0 + p) * 256 + (k >> 1) + 1];
            rp[p][0] = mk2(w0.x, w0.y);
            rp[p][1] = mk2(w0.z, w0.w);
            rp[p][2] = mk2(w1.x, w1.y);
            rp[p][3] = mk2(w1.z, w1.w);
        }
        float4 hq[8];
#pragma unroll
        for (int i = 0; i < 8; ++i)
            hq[i] = h4_s[lane - k + 512 + 64 * i];   // .x=h[A], .y=h[A-1], .z=h[A-2], .w=h[A-3]
#pragma unroll
        for (int p = 0; p < 4; ++p) {
#pragma unroll
            for (int i = 0; i < 8; ++i) {
                f32x2 a = acc[p][i];
                a = __builtin_elementwise_fma(rp[p][0], mk2(hq[i].x, hq[i].x), a);  // u=0
                a = __builtin_elementwise_fma(rp[p][1], mk2(hq[i].y, hq[i].y), a);  // u=1
                a = __builtin_elementwise_fma(rp[p][2], mk2(hq[i].z, hq[i].z), a);  // u=2
                a = __builtin_elementwise_fma(rp[p][3], mk2(hq[i].w, hq[i].w), a);  // u=3
                acc[p][i] = a;
            }
        }
    }

    // Epilogue: de-interleave filtered rows into [16][512] layout, then emit
    // the padded fp32 (c,d) table (R4-verbatim).
    __syncthreads();
#pragma unroll
    for (int p = 0; p < 4; ++p)
#pragma unroll
        for (int i = 0; i < 8; ++i) {
            rows_s[(2 * (pr0 + p)) * 512 + lane + 64 * i]     = acc[p][i].x;
            rows_s[(2 * (pr0 + p) + 1) * 512 + lane + 64 * i] = acc[p][i].y;
        }
    __syncthreads();

    int p = (v < 90) ? v : v - 90;
    int word = (v < 90) ? 0 : 1;
    for (int jj = 0; jj < 16; ++jj) {
        const float* fr = rows_s + jj * 512;
        int slice = b * 32 + half * 16 + jj;
        float* trow = table + (((size_t)slice * 90 + p) * PW) * 4 + word;
        for (int cx = t; cx < PW; cx += 128) {
            int s0 = cx - PADL;
            int i0 = min(max(s0, 0), 511);
            int i1 = min(max(s0 + 1, 0), 511);
            float f0 = fr[i0];
            float d = fr[i1] - f0;
            float m = (float)(cx - TCEN);
            trow[(size_t)cx * 4]     = fmaf(-m, d, f0);   // c
            trow[(size_t)cx * 4 + 2] = d;                 // d
        }
    }
}

// ---------------------------------------------------------------------------
// Kernel C (pair path): orbit backprojection, packed-f32 edition -- R4 EXACT
// (the champion: 422 us, at ~92% of the ds_read_b128 issue-rate model; R9
// showed CHP=1 regresses, R7 showed swizzle regresses, fp16 spills).
// grid = (32 strips, 64 slices), block = 256. Each ds_read_b128 of
// (c_v,c_w,d_v,d_w) serves TWO pixel-angle samples (pair-orbit sharing);
// arithmetic is ONE v_pk_fma_f32 + ONE v_pk_add_f32 per gather.
// Construction rules (9-round bisection): independent per-j iters, f32-only
// register math, __float2int_rd index, NO f16 ops / fractf / serial chain /
// inline asm (each of those scratch-spilled: 3-8 GB HBM signatures).
// ---------------------------------------------------------------------------
__global__ __launch_bounds__(256, 4) void backproj_pair_kernel(const float4* __restrict__ tab,
                                                               const float2* __restrict__ trigp,
                                                               float* __restrict__ out) {
    __shared__ float4 pbuf[CHP * PW];   // 23168 B -> 6 blocks/CU (LDS-capped)
    __shared__ float2 trig_s[90];
    int t = threadIdx.x;
    int slice = blockIdx.y;             // b*32 + r
    int strip = blockIdx.x;             // 0..31
    int y0 = strip * SH3;               // rep-row offset in [0,256)
    const float4* tslice = tab + (size_t)slice * (90 * PW);

    for (int i = t; i < 90; i += 256) trig_s[i] = trigp[i];

    float xc = (float)t + 0.5f;         // rep px = 256+t  ->  xc = px-255.5

    // Packed partials: A<-gather(ua), M<-gather(uma), B<-gather(ub),
    // C<-gather(umb). Component .x = @v contribution, .y = @v+90.
    f32x2 accA[SH3], accM[SH3], accB[SH3], accC[SH3];
#pragma unroll
    for (int j = 0; j < SH3; ++j) {
        accA[j] = mk2(0.f, 0.f); accM[j] = mk2(0.f, 0.f);
        accB[j] = mk2(0.f, 0.f); accC[j] = mk2(0.f, 0.f);
    }

    for (int chunk = 0; chunk < NCHP; ++chunk) {
        __syncthreads();                // previous chunk consumed (covers trig_s on chunk 0)
        const float4* src = tslice + chunk * (CHP * PW);
        for (int i = t; i < CHP * PW; i += 256) pbuf[i] = src[i];
        __syncthreads();
#pragma unroll
        for (int pa = 0; pa < CHP; ++pa) {
            float2 cs = trig_s[chunk * CHP + pa];
            const float4* pb = pbuf + pa * PW + TCEN;
#pragma unroll
            for (int j = 0; j < SH3; ++j) {
                float ycj = (float)(y0 + j) + 0.5f;
                float ua  = fmaf(xc, cs.x, fmaf(ycj, cs.y, -0.5f));   // x c + y s - .5
                float ub  = fmaf(xc, cs.y, fmaf(-ycj, cs.x, -0.5f));  // x s - y c - .5
                int ma = __float2int_rd(ua);                // v_cvt_flr_i32_f32
                int mb = __float2int_rd(ub);
                float uma = -1.0f - ua;                     // u(-a); floor = -2-ma
                float umb = -1.0f - ub;
                float4 qa = pb[ma];
                float4 qm = pb[-2 - ma];
                float4 qb = pb[mb];
                float4 qn = pb[-2 - mb];
                // sample pair = (c_v,c_w) + u*(d_v,d_w): v_pk_fma_f32 + v_pk_add_f32
                accA[j] += __builtin_elementwise_fma(mk2(ua,  ua),  mk2(qa.z, qa.w), mk2(qa.x, qa.y));
                accM[j] += __builtin_elementwise_fma(mk2(uma, uma), mk2(qm.z, qm.w), mk2(qm.x, qm.y));
                accB[j] += __builtin_elementwise_fma(mk2(ub,  ub),  mk2(qb.z, qb.w), mk2(qb.x, qb.y));
                accC[j] += __builtin_elementwise_fma(mk2(umb, umb), mk2(qn.z, qn.w), mk2(qn.x, qn.y));
            }
        }
    }

    // Merge packed partials into the 4 orbit pixels:
    //   P0 = A.x + C.y ; P1 = A.y + B.x ; P2 = M.x + B.y ; P3 = M.y + C.x
    // Orbit writes. P0/P2 are row-coalesced; P1/P3 are per-lane 32B row
    // segments (columns of the orbit) - accepted write amplification.
    int px = 256 + t;
    size_t sbase = (size_t)slice * (512 * 512);
#pragma unroll
    for (int j = 0; j < SH3; ++j) {
        int py = 256 + y0 + j;
        float v0 = accA[j].x + accC[j].y;
        float v1 = accA[j].y + accB[j].x;
        float v2 = accM[j].x + accB[j].y;
        float v3 = accM[j].y + accC[j].x;
        out[sbase + (size_t)py * 512 + px]                   = v0 > 0.f ? v0 : 0.f;  // (x=px,    y=py)
        out[sbase + (size_t)px * 512 + (511 - py)]           = v1 > 0.f ? v1 : 0.f;  // (x=511-py,y=px)
        out[sbase + (size_t)(511 - py) * 512 + (511 - px)]   = v2 > 0.f ? v2 : 0.f;  // (x=511-px,y=511-py)
        out[sbase + (size_t)(511 - px) * 512 + py]           = v3 > 0.f ? v3 : 0.f;  // (x=py,    y=511-px)
    }
}

// ===========================================================================
// Fallback path (round-3 kernels) - used only if ws_size can't hold the table.
// ===========================================================================
__global__ __launch_bounds__(128) void conv_kernel(const float* __restrict__ sino,
                                                   const float* __restrict__ ws,
                                                   float* __restrict__ filt) {
    __shared__ float rows_s[16 * 512];
    __shared__ float h_s[1024];
    int t = threadIdx.x;
    int blk = blockIdx.x;
    int bv = blk >> 1;
    int half = blk & 1;
    int b = bv / 180;
    int v = bv - b * 180;

    const float4* src4 = (const float4*)(sino + (((size_t)bv * 32) + (size_t)half * 16) * 512);
    float4* rows4 = (float4*)rows_s;
    for (int i = t; i < 2048; i += 128) rows4[i] = src4[i];
    for (int i = t; i < 1024; i += 128) h_s[i] = ws[i];
    __syncthreads();

    int wave = t >> 6;
    int lane = t & 63;
    int row0 = wave * 8;

    float acc[8][8];
#pragma unroll
    for (int j = 0; j < 8; ++j)
#pragma unroll
        for (int i = 0; i < 8; ++i) acc[j][i] = 0.f;

    for (int k = 0; k < 512; k += 4) {
        float4 rv[8];
#pragma unroll
        for (int j = 0; j < 8; ++j)
            rv[j] = *(const float4*)&rows_s[(row0 + j) * 512 + k];
#pragma unroll
        for (int u = 0; u < 4; ++u) {
            float hv[8];
            int base = lane - (k + u) + 512;
#pragma unroll
            for (int i = 0; i < 8; ++i) hv[i] = h_s[base + 64 * i];
#pragma unroll
            for (int j = 0; j < 8; ++j) {
                float rj = (u == 0) ? rv[j].x : (u == 1) ? rv[j].y : (u == 2) ? rv[j].z : rv[j].w;
#pragma unroll
                for (int i = 0; i < 8; ++i) acc[j][i] = fmaf(rj, hv[i], acc[j][i]);
            }
        }
    }

#pragma unroll
    for (int j = 0; j < 8; ++j) {
        int r = half * 16 + row0 + j;
        float* dst = filt + (((size_t)b * 32 + r) * 180 + v) * 512;
#pragma unroll
        for (int i = 0; i < 8; ++i) dst[lane + 64 * i] = acc[j][i];
    }
}

__global__ __launch_bounds__(256) void backproj_kernel(const float* __restrict__ filt,
                                                       const float* __restrict__ trig,
                                                       float* __restrict__ out) {
    __shared__ float2 pbuf[CH2][PW];
    __shared__ float trig_s[360];
    int t = threadIdx.x;
    int slice = blockIdx.y;
    int strip = blockIdx.x;
    int y0 = strip * SH;
    int lane = t & 63;
    int wave = t >> 6;
    int x0 = wave * 128;
    const float* slice_p = filt + (size_t)slice * (180 * 512);

    for (int i = t; i < 360; i += 256) trig_s[i] = trig[i];

    float xc0 = (float)(x0 + lane) - 255.5f;
    float xc1 = xc0 + 64.0f;
    float yb0 = (float)y0 - 255.5f;

    float acc[2][SH];
#pragma unroll
    for (int g = 0; g < 2; ++g)
#pragma unroll
        for (int j = 0; j < SH; ++j) acc[g][j] = 0.f;

    for (int chunk = 0; chunk < NCHUNK2; ++chunk) {
        int v0 = chunk * CH2;
        __syncthreads();
#pragma unroll 1
        for (int a = 0; a < CH2; ++a) {
            const float* prow = slice_p + (v0 + a) * 512;
            for (int cx = t; cx < PW; cx += 256) {
                int s0 = cx - PADL;
                int i0 = min(max(s0, 0), 511);
                int i1 = min(max(s0 + 1, 0), 511);
                float f0 = prow[i0];
                float d = prow[i1] - f0;
                float m = (float)(cx - TCEN);
                pbuf[a][cx] = make_float2(fmaf(-m, d, f0), d);
            }
        }
        __syncthreads();
#pragma unroll 1
        for (int a = 0; a < CH2; ++a) {
            float cth = trig_s[v0 + a];
            float sth = trig_s[180 + v0 + a];
            float ybase = fmaf(yb0, sth, 255.5f + (float)PADL - (float)TCEN);
            float t0 = fmaf(xc0, cth, ybase);
            float t1 = fmaf(xc1, cth, ybase);
            const char* pb = (const char*)pbuf;
            int aoff = a * (PW * 8) + TCEN * 8;
#pragma unroll
            for (int j = 0; j < SH; ++j) {
                int m0 = (int)floorf(t0);
                float2 g0 = *(const float2*)(pb + (m0 * 8 + aoff));
                acc[0][j] = fmaf(t0, g0.y, acc[0][j]) + g0.x;
                t0 += sth;

                int m1 = (int)floorf(t1);
                float2 g1 = *(const float2*)(pb + (m1 * 8 + aoff));
                acc[1][j] = fmaf(t1, g1.y, acc[1][j]) + g1.x;
                t1 += sth;
            }
        }
    }

    size_t obase = ((size_t)slice * 512 + (size_t)y0) * 512;
#pragma unroll
    for (int j = 0; j < SH; ++j) {
        float v0o = acc[0][j];
        float v1o = acc[1][j];
        out[obase + (size_t)j * 512 + x0 + lane] = v0o > 0.f ? v0o : 0.f;
        out[obase + (size_t)j * 512 + x0 + 64 + lane] = v1o > 0.f ? v1o : 0.f;
    }
}

extern "C" void kernel_launch(void* const* d_in, const int* in_sizes, int n_in,
                              void* d_out, int out_size, void* d_ws, size_t ws_size,
                              hipStream_t stream) {
    const float* sino = (const float*)d_in[0];
    float* out = (float*)d_out;
    float* ws = (float*)d_ws;

    size_t tableFloats = (size_t)64 * 90 * PW * 4;             // 16.68M floats
    size_t needed = ((size_t)TAB_OFF + tableFloats) * 4;       // ~66.7 MB

    precompute_kernel<<<2, 256, 0, stream>>>(ws);
    if (ws_size >= needed) {
        float* table = ws + TAB_OFF;
        precompute_h4_kernel<<<4, 256, 0, stream>>>(ws);
        conv_table_kernel<<<720, 128, 0, stream>>>(sino, ws, table);
        backproj_pair_kernel<<<dim3(32, 64), 256, 0, stream>>>((const float4*)table,
                                                               (const float2*)(ws + 1408), out);
    } else {
        float* filt = ws + FILT_OFF;
        conv_kernel<<<720, 128, 0, stream>>>(sino, ws, filt);
        backproj_kernel<<<dim3(32, 64), 256, 0, stream>>>(filt, ws + 1024, out);
    }
}